// Round 1
// baseline (425.872 us; speedup 1.0000x reference)
//
#include <hip/hip_runtime.h>
#include <math.h>

// Problem constants (B=2, L=2048, H=16, D=64, HID=1024, NB=4)
#define NBL   4096      // B*L
#define NPOS  65536     // B*L*H
#define TWO_D 128
#define HIDN  1024

// ws layout (floats):
//   wsum : [12][128]          column sums of W1 stat rows
//   hidT : [4096][128]        hidden @ W1[:1024]
//   stats: [65536][12]        (mean, rms, max) x 4 branches per position

// ---------------------------------------------------------------- K1: wsum
__global__ __launch_bounds__(128) void k_wsum(const float* __restrict__ W1,
                                              float* __restrict__ wsum) {
    const int o = threadIdx.x;          // 0..127
    const int i = blockIdx.x;           // 0..11  (j*3+s)
    const int j = i / 3, s = i - 3 * j;
    const int rowbase = HIDN + j * 192 + s * 64;
    float acc = 0.f;
    #pragma unroll
    for (int d = 0; d < 64; ++d)
        acc += W1[(size_t)(rowbase + d) * TWO_D + o];
    wsum[i * TWO_D + o] = acc;
}

// ---------------------------------------------------------------- K2: hidden GEMM
// hidT[r][o] = sum_k hidden[r][k] * W1[k][o],  r in [0,4096), o in [0,128)
// block: 256 threads = (o:128) x (kg:2 split-K halves); 16 rows per block.
__global__ __launch_bounds__(256) void k_hid(const float* __restrict__ hidden,
                                             const float* __restrict__ W1,
                                             float* __restrict__ hidT) {
    __shared__ float part[16][TWO_D];
    const int t  = threadIdx.x;
    const int o  = t & 127;
    const int kg = __builtin_amdgcn_readfirstlane(t >> 7);  // wave-uniform
    const int r0 = blockIdx.x * 16;

    float acc[16];
    #pragma unroll
    for (int p = 0; p < 16; ++p) acc[p] = 0.f;

    for (int c = 0; c < 8; ++c) {
        const int kbase = kg * 512 + c * 64;
        float w[64];
        #pragma unroll
        for (int kk = 0; kk < 64; ++kk)
            w[kk] = W1[(size_t)(kbase + kk) * TWO_D + o];   // coalesced over o
        #pragma unroll
        for (int p = 0; p < 16; ++p) {
            const float4* hp = (const float4*)(hidden + (size_t)(r0 + p) * HIDN + kbase);
            #pragma unroll
            for (int k4 = 0; k4 < 16; ++k4) {
                const float4 xv = hp[k4];                   // wave-uniform address
                acc[p] = fmaf(xv.x, w[4 * k4 + 0], acc[p]);
                acc[p] = fmaf(xv.y, w[4 * k4 + 1], acc[p]);
                acc[p] = fmaf(xv.z, w[4 * k4 + 2], acc[p]);
                acc[p] = fmaf(xv.w, w[4 * k4 + 3], acc[p]);
            }
        }
    }

    if (kg == 1) {
        #pragma unroll
        for (int p = 0; p < 16; ++p) part[p][o] = acc[p];
    }
    __syncthreads();
    if (kg == 0) {
        #pragma unroll
        for (int p = 0; p < 16; ++p)
            hidT[(size_t)(r0 + p) * TWO_D + o] = acc[p] + part[p][o];
    }
}

// ---------------------------------------------------------------- K3: per-position stats
// One wave per position; lane: j = lane>>4 (branch), sub = lane&15 (4 elems each).
__global__ __launch_bounds__(256) void k_stats(const float* __restrict__ g0,
                                               const float* __restrict__ g1,
                                               const float* __restrict__ g2,
                                               const float* __restrict__ g3,
                                               float* __restrict__ stats) {
    const int t    = threadIdx.x;
    const int wave = t >> 6;
    const int lane = t & 63;
    const int pos  = blockIdx.x * 4 + wave;   // < 65536
    const int j    = lane >> 4;
    const int sub  = lane & 15;
    const float* bp = (j == 0) ? g0 : (j == 1) ? g1 : (j == 2) ? g2 : g3;
    const float4 v = *(const float4*)(bp + (size_t)pos * 64 + sub * 4);

    float s  = v.x + v.y + v.z + v.w;
    float sq = v.x * v.x + v.y * v.y + v.z * v.z + v.w * v.w;
    float mx = fmaxf(fmaxf(v.x, v.y), fmaxf(v.z, v.w));
    #pragma unroll
    for (int off = 1; off < 16; off <<= 1) {
        s  += __shfl_xor(s, off);
        sq += __shfl_xor(sq, off);
        mx  = fmaxf(mx, __shfl_xor(mx, off));
    }
    if (sub == 0) {
        float* sp = stats + (size_t)pos * 12 + j * 3;
        sp[0] = s * (1.f / 64.f);
        sp[1] = sqrtf(fmaxf(sq * (1.f / 64.f), 1e-8f));
        sp[2] = mx;
    }
}

// ---------------------------------------------------------------- K4: branch GEMM + epilogue
// One block per (b,l): 16 heads. 256 threads = (o:128) x (kg:2 K-halves).
__global__ __launch_bounds__(256) void k_main(
    const float* __restrict__ g0, const float* __restrict__ g1,
    const float* __restrict__ g2, const float* __restrict__ g3,
    const float* __restrict__ W1, const float* __restrict__ b1,
    const float* __restrict__ W2, const float* __restrict__ b2,
    const float* __restrict__ eps_floor, const float* __restrict__ temp,
    const float* __restrict__ wsum, const float* __restrict__ hidT,
    const float* __restrict__ stats, float* __restrict__ out) {

    __shared__ float gbuf[16][TWO_D];
    __shared__ float red[64][4];
    __shared__ float lgs[64];

    const int t  = threadIdx.x;
    const int o  = t & 127;
    const int kg = __builtin_amdgcn_readfirstlane(t >> 7);
    const int bl = blockIdx.x;                       // 0..4095

    float acc[16];
    #pragma unroll
    for (int p = 0; p < 16; ++p) acc[p] = 0.f;

    #pragma unroll
    for (int c = 0; c < 2; ++c) {
        const int j = kg * 2 + c;                    // branch index, wave-uniform
        const float* __restrict__ bj = (j == 0) ? g0 : (j == 1) ? g1 : (j == 2) ? g2 : g3;
        float w[64];
        #pragma unroll
        for (int kk = 0; kk < 64; ++kk)
            w[kk] = W1[(size_t)(1792 + j * 64 + kk) * TWO_D + o];
        #pragma unroll
        for (int p = 0; p < 16; ++p) {
            const float4* xp = (const float4*)(bj + ((size_t)bl * 16 + p) * 64);
            #pragma unroll
            for (int k4 = 0; k4 < 16; ++k4) {
                const float4 xv = xp[k4];            // wave-uniform address
                acc[p] = fmaf(xv.x, w[4 * k4 + 0], acc[p]);
                acc[p] = fmaf(xv.y, w[4 * k4 + 1], acc[p]);
                acc[p] = fmaf(xv.z, w[4 * k4 + 2], acc[p]);
                acc[p] = fmaf(xv.w, w[4 * k4 + 3], acc[p]);
            }
        }
    }

    if (kg == 1) {
        #pragma unroll
        for (int p = 0; p < 16; ++p) gbuf[p][o] = acc[p];
    }
    __syncthreads();

    if (kg == 0) {
        const float hv  = hidT[(size_t)bl * TWO_D + o];
        const float b1v = b1[o];
        float wsv[12];
        #pragma unroll
        for (int i = 0; i < 12; ++i) wsv[i] = wsum[i * TWO_D + o];
        #pragma unroll
        for (int p = 0; p < 16; ++p) {
            const float* sp = stats + ((size_t)bl * 16 + p) * 12;
            float x = acc[p] + gbuf[p][o] + hv + b1v;
            #pragma unroll
            for (int i = 0; i < 12; ++i) x = fmaf(sp[i], wsv[i], x);
            // exact GELU (approximate=False): 0.5*x*(1+erf(x/sqrt(2)))
            const float g = 0.5f * x * (1.0f + erff(x * 0.7071067811865476f));
            gbuf[p][o] = g;
        }
    }
    __syncthreads();

    // logits: 64 sums (16 heads x 4 outputs) of 128 each; 4 threads per sum.
    {
        const int sid = t >> 2;      // 0..63 = p*4+n
        const int q   = t & 3;
        const int p   = sid >> 2;
        const int n   = sid & 3;
        float partial = 0.f;
        #pragma unroll
        for (int i = 0; i < 32; ++i) {
            const int oo = q * 32 + i;
            partial = fmaf(gbuf[p][oo], W2[oo * 4 + n], partial);
        }
        red[sid][q] = partial;
    }
    __syncthreads();
    if (t < 64)
        lgs[t] = red[t][0] + red[t][1] + red[t][2] + red[t][3] + b2[t & 3];
    __syncthreads();

    // softmax + floor + renorm: one thread per head
    if (t < 16) {
        const int p = t;             // head index
        const float l0 = lgs[p * 4 + 0], l1 = lgs[p * 4 + 1];
        const float l2 = lgs[p * 4 + 2], l3 = lgs[p * 4 + 3];
        const float tc  = fminf(fmaxf(temp[p], 0.2f), 10.0f);
        const float inv = 1.0f / tc;
        const float m = fmaxf(fmaxf(l0, l1), fmaxf(l2, l3));
        float e0 = expf((l0 - m) * inv);
        float e1 = expf((l1 - m) * inv);
        float e2 = expf((l2 - m) * inv);
        float e3 = expf((l3 - m) * inv);
        const float rsum = 1.0f / (e0 + e1 + e2 + e3);
        float w0 = e0 * rsum, w1 = e1 * rsum, w2 = e2 * rsum, w3 = e3 * rsum;
        w0 = fmaxf(w0, fminf(fmaxf(eps_floor[p * 4 + 0], 1e-7f), 0.1f));
        w1 = fmaxf(w1, fminf(fmaxf(eps_floor[p * 4 + 1], 1e-7f), 0.1f));
        w2 = fmaxf(w2, fminf(fmaxf(eps_floor[p * 4 + 2], 1e-7f), 0.1f));
        w3 = fmaxf(w3, fminf(fmaxf(eps_floor[p * 4 + 3], 1e-7f), 0.1f));
        const float rs = 1.0f / (w0 + w1 + w2 + w3);
        float4 ov;
        ov.x = w0 * rs; ov.y = w1 * rs; ov.z = w2 * rs; ov.w = w3 * rs;
        *(float4*)(out + ((size_t)bl * 16 + p) * 4) = ov;
    }
}

// ---------------------------------------------------------------- launch
extern "C" void kernel_launch(void* const* d_in, const int* in_sizes, int n_in,
                              void* d_out, int out_size, void* d_ws, size_t ws_size,
                              hipStream_t stream) {
    const float* hidden = (const float*)d_in[0];
    const float* br0    = (const float*)d_in[1];
    const float* br1    = (const float*)d_in[2];
    const float* br2    = (const float*)d_in[3];
    const float* br3    = (const float*)d_in[4];
    const float* W1     = (const float*)d_in[5];
    const float* b1     = (const float*)d_in[6];
    const float* W2     = (const float*)d_in[7];
    const float* b2     = (const float*)d_in[8];
    const float* eps    = (const float*)d_in[9];
    const float* temp   = (const float*)d_in[10];
    float* out = (float*)d_out;

    float* ws    = (float*)d_ws;
    float* wsum  = ws;                                   // 12*128
    float* hidT  = ws + 12 * 128;                        // 4096*128
    float* stats = hidT + (size_t)NBL * TWO_D;           // 65536*12

    hipLaunchKernelGGL(k_wsum,  dim3(12),    dim3(128), 0, stream, W1, wsum);
    hipLaunchKernelGGL(k_hid,   dim3(256),   dim3(256), 0, stream, hidden, W1, hidT);
    hipLaunchKernelGGL(k_stats, dim3(16384), dim3(256), 0, stream, br0, br1, br2, br3, stats);
    hipLaunchKernelGGL(k_main,  dim3(4096),  dim3(256), 0, stream,
                       br0, br1, br2, br3, W1, b1, W2, b2, eps, temp,
                       wsum, hidT, stats, out);
}

// Round 2
// 301.307 us; speedup vs baseline: 1.4134x; 1.4134x over previous
//
#include <hip/hip_runtime.h>
#include <math.h>

// Problem constants (B=2, L=2048, H=16, D=64, HID=1024, NB=4)
#define NBL   4096      // B*L
#define NPOS  65536     // B*L*H
#define TWO_D 128
#define HIDN  1024

// ws layout (floats):
//   wsum : [12][128]        column sums of W1 stat rows           (1536)
//   P0   : [4096][128]      hid partial (K 0..511); becomes hidT  (524288)
//   P1   : [4096][128]      hid partial (K 512..1023)             (524288)
// total 4.2 MB

// ---------------------------------------------------------------- K1: wsum
__global__ __launch_bounds__(128) void k_wsum(const float* __restrict__ W1,
                                              float* __restrict__ wsum) {
    const int o = threadIdx.x;          // 0..127
    const int i = blockIdx.x;           // 0..11  (j*3+s)
    const int j = i / 3, s = i - 3 * j;
    const int rowbase = HIDN + j * 192 + s * 64;
    float acc = 0.f;
    #pragma unroll
    for (int d = 0; d < 64; ++d)
        acc += W1[(size_t)(rowbase + d) * TWO_D + o];
    wsum[i * TWO_D + o] = acc;
}

// ---------------------------------------------------------------- K2: hidden GEMM partials
// grid 1024: bx -> ks = bx&1 (K half), rg = bx>>1 (8-row group).
// block 256 = o(128) x kg(2).  Each (o,kg): 8 rows x 256 K.
__global__ __launch_bounds__(256) void k_hid(const float* __restrict__ hidden,
                                             const float* __restrict__ W1,
                                             float* __restrict__ hP0,
                                             float* __restrict__ hP1) {
    __shared__ float part[8][TWO_D];
    const int t  = threadIdx.x;
    const int o  = t & 127;
    const int kg = __builtin_amdgcn_readfirstlane(t >> 7);
    const int ks = blockIdx.x & 1;
    const int rg = blockIdx.x >> 1;
    const int r0 = rg * 8;
    const int kbase0 = ks * 512 + kg * 256;

    float acc[8];
    #pragma unroll
    for (int p = 0; p < 8; ++p) acc[p] = 0.f;

    for (int c = 0; c < 4; ++c) {              // runtime loop: small body, I$-safe
        const int kb = kbase0 + c * 64;
        float wv[64];
        #pragma unroll
        for (int kk = 0; kk < 64; ++kk)
            wv[kk] = W1[(size_t)(kb + kk) * TWO_D + o];     // coalesced over o
        #pragma unroll
        for (int p = 0; p < 8; ++p) {
            const float4* hp = (const float4*)(hidden + (size_t)(r0 + p) * HIDN + kb);
            #pragma unroll
            for (int k4 = 0; k4 < 16; ++k4) {
                const float4 xv = hp[k4];                   // uniform -> scalar load
                acc[p] = fmaf(xv.x, wv[4 * k4 + 0], acc[p]);
                acc[p] = fmaf(xv.y, wv[4 * k4 + 1], acc[p]);
                acc[p] = fmaf(xv.z, wv[4 * k4 + 2], acc[p]);
                acc[p] = fmaf(xv.w, wv[4 * k4 + 3], acc[p]);
            }
        }
    }

    if (kg == 1) {
        #pragma unroll
        for (int p = 0; p < 8; ++p) part[p][o] = acc[p];
    }
    __syncthreads();
    if (kg == 0) {
        float* dst = ks ? hP1 : hP0;
        #pragma unroll
        for (int p = 0; p < 8; ++p)
            dst[(size_t)(r0 + p) * TWO_D + o] = acc[p] + part[p][o];
    }
}

// ---------------------------------------------------------------- K3: reduce partials (P0 += P1)
__global__ __launch_bounds__(256) void k_hidred(float* __restrict__ hP0,
                                                const float* __restrict__ hP1) {
    const int i = blockIdx.x * 256 + threadIdx.x;   // < 524288
    hP0[i] += hP1[i];
}

// ---------------------------------------------------------------- K4: main (lane = position)
// grid 512 blocks x 256 threads. Block covers 128 positions.
// wave w: og = w&1 (o-half), pg = w>>1 (position group of 64).
// Each lane owns one position: acc[64] = its o-half of h1 pre-activation.
__global__ __launch_bounds__(256) void k_main(
    const float* __restrict__ g0, const float* __restrict__ g1,
    const float* __restrict__ g2, const float* __restrict__ g3,
    const float* __restrict__ W1, const float* __restrict__ b1,
    const float* __restrict__ W2, const float* __restrict__ b2,
    const float* __restrict__ eps_floor, const float* __restrict__ temp,
    const float* __restrict__ wsum, const float* __restrict__ hidT,
    float* __restrict__ out) {

    __shared__ float4 lp[4][64];

    const int t    = threadIdx.x;
    const int lane = t & 63;
    const int w    = __builtin_amdgcn_readfirstlane(t >> 6);  // wave id, uniform
    const int og   = w & 1;                                   // o-half, uniform
    const int pg   = w >> 1;                                  // position group
    const int pos  = blockIdx.x * 128 + pg * 64 + lane;       // per-lane position
    const int ocol = og * 64;                                 // uniform

    float acc[64];
    #pragma unroll
    for (int o = 0; o < 64; ++o) acc[o] = 0.f;

    for (int j = 0; j < 4; ++j) {                 // runtime, uniform
        const float* __restrict__ bj = (j == 0) ? g0 : (j == 1) ? g1 : (j == 2) ? g2 : g3;
        const float* __restrict__ xrow = bj + (size_t)pos * 64;   // per-lane, coalesced
        float s = 0.f, sq = 0.f, mx = -INFINITY;

        for (int ko = 0; ko < 8; ++ko) {          // runtime: body ~600 instrs
            const float4 a = *(const float4*)(xrow + ko * 8);
            const float4 b = *(const float4*)(xrow + ko * 8 + 4);
            float x8[8] = {a.x, a.y, a.z, a.w, b.x, b.y, b.z, b.w};
            #pragma unroll
            for (int kk = 0; kk < 8; ++kk) {
                s  += x8[kk];
                sq  = fmaf(x8[kk], x8[kk], sq);
                mx  = fmaxf(mx, x8[kk]);
            }
            const float* __restrict__ wbase =
                W1 + (size_t)(1792 + j * 64 + ko * 8) * TWO_D + ocol;  // uniform
            #pragma unroll
            for (int kk = 0; kk < 8; ++kk) {
                const float* __restrict__ wr = wbase + kk * TWO_D;     // uniform -> s_load
                #pragma unroll
                for (int o = 0; o < 64; ++o)
                    acc[o] = fmaf(x8[kk], wr[o], acc[o]);
            }
        }

        // fold this branch's stat contributions (rank-3 update via wsum)
        const float mean = s * (1.f / 64.f);
        const float rms  = sqrtf(fmaxf(sq * (1.f / 64.f), 1e-8f));
        const float* __restrict__ wm = wsum + (j * 3 + 0) * TWO_D + ocol;  // uniform
        const float* __restrict__ wr = wsum + (j * 3 + 1) * TWO_D + ocol;
        const float* __restrict__ wx = wsum + (j * 3 + 2) * TWO_D + ocol;
        #pragma unroll
        for (int o = 0; o < 64; ++o) {
            acc[o] = fmaf(mean, wm[o], acc[o]);
            acc[o] = fmaf(rms,  wr[o], acc[o]);
            acc[o] = fmaf(mx,   wx[o], acc[o]);
        }
    }

    // epilogue: + hidT + b1, GELU, partial logits (this o-half)
    const float* __restrict__ hrow = hidT + (size_t)(pos >> 4) * TWO_D + ocol; // per-lane
    const float* __restrict__ b1p  = b1 + ocol;                                // uniform
    float p0 = 0.f, p1 = 0.f, p2 = 0.f, p3 = 0.f;
    #pragma unroll
    for (int o = 0; o < 64; ++o) {
        const float x = acc[o] + hrow[o] + b1p[o];
        const float g = 0.5f * x * (1.0f + erff(x * 0.7071067811865476f));
        const float* __restrict__ w2r = W2 + (ocol + o) * 4;   // uniform
        p0 = fmaf(g, w2r[0], p0);
        p1 = fmaf(g, w2r[1], p1);
        p2 = fmaf(g, w2r[2], p2);
        p3 = fmaf(g, w2r[3], p3);
    }

    float4 mine; mine.x = p0; mine.y = p1; mine.z = p2; mine.w = p3;
    lp[w][lane] = mine;
    __syncthreads();

    if (og == 0) {                                // waves 0 and 2 finish their positions
        const float4 q = lp[w + 1][lane];
        const float l0 = p0 + q.x + b2[0];
        const float l1 = p1 + q.y + b2[1];
        const float l2 = p2 + q.z + b2[2];
        const float l3 = p3 + q.w + b2[3];

        const int h = pos & 15;
        const float tc  = fminf(fmaxf(temp[h], 0.2f), 10.0f);
        const float inv = 1.0f / tc;
        const float m = fmaxf(fmaxf(l0, l1), fmaxf(l2, l3));
        float e0 = expf((l0 - m) * inv);
        float e1 = expf((l1 - m) * inv);
        float e2 = expf((l2 - m) * inv);
        float e3 = expf((l3 - m) * inv);
        const float rsum = 1.0f / (e0 + e1 + e2 + e3);
        float w0 = e0 * rsum, w1 = e1 * rsum, w2 = e2 * rsum, w3 = e3 * rsum;
        const float4 ef = *(const float4*)(eps_floor + h * 4);
        w0 = fmaxf(w0, fminf(fmaxf(ef.x, 1e-7f), 0.1f));
        w1 = fmaxf(w1, fminf(fmaxf(ef.y, 1e-7f), 0.1f));
        w2 = fmaxf(w2, fminf(fmaxf(ef.z, 1e-7f), 0.1f));
        w3 = fmaxf(w3, fminf(fmaxf(ef.w, 1e-7f), 0.1f));
        const float rs = 1.0f / (w0 + w1 + w2 + w3);
        float4 ov;
        ov.x = w0 * rs; ov.y = w1 * rs; ov.z = w2 * rs; ov.w = w3 * rs;
        *(float4*)(out + (size_t)pos * 4) = ov;                // coalesced
    }
}

// ---------------------------------------------------------------- launch
extern "C" void kernel_launch(void* const* d_in, const int* in_sizes, int n_in,
                              void* d_out, int out_size, void* d_ws, size_t ws_size,
                              hipStream_t stream) {
    const float* hidden = (const float*)d_in[0];
    const float* br0    = (const float*)d_in[1];
    const float* br1    = (const float*)d_in[2];
    const float* br2    = (const float*)d_in[3];
    const float* br3    = (const float*)d_in[4];
    const float* W1     = (const float*)d_in[5];
    const float* b1     = (const float*)d_in[6];
    const float* W2     = (const float*)d_in[7];
    const float* b2     = (const float*)d_in[8];
    const float* eps    = (const float*)d_in[9];
    const float* temp   = (const float*)d_in[10];
    float* out = (float*)d_out;

    float* ws   = (float*)d_ws;
    float* wsum = ws;                         // 1536
    float* hP0  = ws + 1536;                  // 524288 (becomes hidT)
    float* hP1  = hP0 + (size_t)NBL * TWO_D;  // 524288

    hipLaunchKernelGGL(k_wsum,   dim3(12),   dim3(128), 0, stream, W1, wsum);
    hipLaunchKernelGGL(k_hid,    dim3(1024), dim3(256), 0, stream, hidden, W1, hP0, hP1);
    hipLaunchKernelGGL(k_hidred, dim3(2048), dim3(256), 0, stream, hP0, hP1);
    hipLaunchKernelGGL(k_main,   dim3(512),  dim3(256), 0, stream,
                       br0, br1, br2, br3, W1, b1, W2, b2, eps, temp,
                       wsum, hP0, out);
}

// Round 3
// 207.642 us; speedup vs baseline: 2.0510x; 1.4511x over previous
//
#include <hip/hip_runtime.h>
#include <math.h>

// Problem constants (B=2, L=2048, H=16, D=64, HID=1024, NB=4)
#define NBL   4096      // B*L
#define NPOS  65536     // B*L*H
#define TWO_D 128
#define HIDN  1024

typedef __attribute__((ext_vector_type(8))) short short8;  // 8 bf16 (4 VGPRs)
typedef __attribute__((ext_vector_type(4))) float f32x4;   // MFMA accumulator

// fp32 -> bf16, round-to-nearest-even (finite inputs)
__device__ inline short f2bf(float f) {
    union { float f; unsigned u; } v; v.f = f;
    unsigned r = (v.u + 0x7FFFu + ((v.u >> 16) & 1u)) >> 16;
    return (short)r;
}

// ws layout:
//   hP0  : float [4096][128]   hid partial K0..511 -> becomes hidT   (2 MB)
//   hP1  : float [4096][128]   hid partial K512..1023               (2 MB)
//   WhT  : bf16  [128][1024]   W1 hid part, transposed              (256 KB)
//   WbT  : bf16  [128][256]    W1 branch part, transposed           (64 KB)
//   wsT  : bf16  [128][32]     stat column-sums, transposed, padded (8 KB)

// ---------------------------------------------------------------- K0: weight prep
__global__ __launch_bounds__(64) void k_prep(const float* __restrict__ W1,
                                             short* __restrict__ WhT,
                                             short* __restrict__ WbT,
                                             short* __restrict__ wsT) {
    const int n = blockIdx.x;      // output column 0..127
    const int t = threadIdx.x;     // 0..63
    for (int kb = 0; kb < 16; ++kb) {
        const int k = kb * 64 + t;
        WhT[n * 1024 + k] = f2bf(W1[(size_t)k * TWO_D + n]);
    }
    for (int kb = 0; kb < 4; ++kb) {
        const int k = kb * 64 + t;
        WbT[n * 256 + k] = f2bf(W1[(size_t)(1792 + k) * TWO_D + n]);
    }
    if (t < 32) {
        float s = 0.f;
        if (t < 12) {
            const int j = t / 3, st = t - 3 * j;
            const int base = HIDN + j * 192 + st * 64;
            for (int d = 0; d < 64; ++d) s += W1[(size_t)(base + d) * TWO_D + n];
        }
        wsT[n * 32 + t] = (t < 12) ? f2bf(s) : (short)0;
    }
}

// ---------------------------------------------------------------- K1: hid GEMM (MFMA)
// grid 256: ks = bx&1 (K half), mtp = bx>>1 (pair of 16-row m-tiles).
// 1 wave: 2 m-tiles x 8 n-tiles, K=512 (16 k-steps of 32).
__global__ __launch_bounds__(64) void k_hid(const float* __restrict__ hidden,
                                            const short* __restrict__ WhT,
                                            float* __restrict__ hP0,
                                            float* __restrict__ hP1) {
    const int lane = threadIdx.x;
    const int quad = lane >> 4, lm = lane & 15;
    const int ks   = blockIdx.x & 1;
    const int mtp  = blockIdx.x >> 1;   // 0..127

    f32x4 acc[2][8];
    #pragma unroll
    for (int mt = 0; mt < 2; ++mt)
        #pragma unroll
        for (int nt = 0; nt < 8; ++nt)
            acc[mt][nt] = (f32x4){0.f, 0.f, 0.f, 0.f};

    for (int kk = 0; kk < 16; ++kk) {
        const int k0 = ks * 512 + kk * 32 + quad * 8;
        short8 a[2];
        #pragma unroll
        for (int mt = 0; mt < 2; ++mt) {
            const int bl = (mtp * 2 + mt) * 16 + lm;
            const float4 x0 = *(const float4*)(hidden + (size_t)bl * HIDN + k0);
            const float4 x1 = *(const float4*)(hidden + (size_t)bl * HIDN + k0 + 4);
            a[mt][0] = f2bf(x0.x); a[mt][1] = f2bf(x0.y);
            a[mt][2] = f2bf(x0.z); a[mt][3] = f2bf(x0.w);
            a[mt][4] = f2bf(x1.x); a[mt][5] = f2bf(x1.y);
            a[mt][6] = f2bf(x1.z); a[mt][7] = f2bf(x1.w);
        }
        #pragma unroll
        for (int nt = 0; nt < 8; ++nt) {
            const short8 b = *(const short8*)(WhT + (size_t)(nt * 16 + lm) * 1024 + k0);
            acc[0][nt] = __builtin_amdgcn_mfma_f32_16x16x32_bf16(a[0], b, acc[0][nt], 0, 0, 0);
            acc[1][nt] = __builtin_amdgcn_mfma_f32_16x16x32_bf16(a[1], b, acc[1][nt], 0, 0, 0);
        }
    }

    float* __restrict__ dst = ks ? hP1 : hP0;
    #pragma unroll
    for (int mt = 0; mt < 2; ++mt)
        #pragma unroll
        for (int nt = 0; nt < 8; ++nt)
            #pragma unroll
            for (int r = 0; r < 4; ++r) {
                const int bl = (mtp * 2 + mt) * 16 + quad * 4 + r;   // C row
                dst[(size_t)bl * TWO_D + nt * 16 + lm] = acc[mt][nt][r];
            }
}

// ---------------------------------------------------------------- K2: reduce partials
__global__ __launch_bounds__(256) void k_hidred(float* __restrict__ hP0,
                                                const float* __restrict__ hP1) {
    const int i = blockIdx.x * 256 + threadIdx.x;   // < 524288
    hP0[i] += hP1[i];
}

// ---------------------------------------------------------------- K3: main fused kernel
// grid 2048, 1 wave. Block: 2 m-tiles (32 positions; each m-tile = one (b,l)),
// 8 n-tiles (128 outputs). Branch GEMM K=256 + 1 stat k-step, then epilogue.
__global__ __launch_bounds__(64) void k_main(
    const float* __restrict__ g0, const float* __restrict__ g1,
    const float* __restrict__ g2, const float* __restrict__ g3,
    const short* __restrict__ WbT, const short* __restrict__ wsT,
    const float* __restrict__ b1, const float* __restrict__ W2,
    const float* __restrict__ b2, const float* __restrict__ eps_floor,
    const float* __restrict__ temp, const float* __restrict__ hidT,
    float* __restrict__ out) {

    const int lane = threadIdx.x;
    const int quad = lane >> 4, lm = lane & 15;
    const int tile0 = blockIdx.x * 2;               // global m-tile = (b,l) index

    f32x4 acc[2][8];
    #pragma unroll
    for (int mt = 0; mt < 2; ++mt)
        #pragma unroll
        for (int nt = 0; nt < 8; ++nt)
            acc[mt][nt] = (f32x4){0.f, 0.f, 0.f, 0.f};

    float stm[2][12];                               // per-row stats (post-reduce)

    const float* const bjs[4] = {g0, g1, g2, g3};
    #pragma unroll
    for (int j = 0; j < 4; ++j) {
        const float* __restrict__ bj = bjs[j];
        float s[2] = {0.f, 0.f}, sq[2] = {0.f, 0.f}, mx[2] = {-INFINITY, -INFINITY};
        #pragma unroll
        for (int half = 0; half < 2; ++half) {
            const int kc = half * 32 + quad * 8;    // col within branch row
            short8 a[2];
            #pragma unroll
            for (int mt = 0; mt < 2; ++mt) {
                const int pos = (tile0 + mt) * 16 + lm;
                const float4 x0 = *(const float4*)(bj + (size_t)pos * 64 + kc);
                const float4 x1 = *(const float4*)(bj + (size_t)pos * 64 + kc + 4);
                s[mt]  += x0.x + x0.y + x0.z + x0.w + x1.x + x1.y + x1.z + x1.w;
                sq[mt]  = fmaf(x0.x, x0.x, sq[mt]); sq[mt] = fmaf(x0.y, x0.y, sq[mt]);
                sq[mt]  = fmaf(x0.z, x0.z, sq[mt]); sq[mt] = fmaf(x0.w, x0.w, sq[mt]);
                sq[mt]  = fmaf(x1.x, x1.x, sq[mt]); sq[mt] = fmaf(x1.y, x1.y, sq[mt]);
                sq[mt]  = fmaf(x1.z, x1.z, sq[mt]); sq[mt] = fmaf(x1.w, x1.w, sq[mt]);
                mx[mt]  = fmaxf(mx[mt], fmaxf(fmaxf(x0.x, x0.y), fmaxf(x0.z, x0.w)));
                mx[mt]  = fmaxf(mx[mt], fmaxf(fmaxf(x1.x, x1.y), fmaxf(x1.z, x1.w)));
                a[mt][0] = f2bf(x0.x); a[mt][1] = f2bf(x0.y);
                a[mt][2] = f2bf(x0.z); a[mt][3] = f2bf(x0.w);
                a[mt][4] = f2bf(x1.x); a[mt][5] = f2bf(x1.y);
                a[mt][6] = f2bf(x1.z); a[mt][7] = f2bf(x1.w);
            }
            const int kg = j * 64 + half * 32 + quad * 8;   // col within WbT row
            #pragma unroll
            for (int nt = 0; nt < 8; ++nt) {
                const short8 b = *(const short8*)(WbT + (size_t)(nt * 16 + lm) * 256 + kg);
                acc[0][nt] = __builtin_amdgcn_mfma_f32_16x16x32_bf16(a[0], b, acc[0][nt], 0, 0, 0);
                acc[1][nt] = __builtin_amdgcn_mfma_f32_16x16x32_bf16(a[1], b, acc[1][nt], 0, 0, 0);
            }
        }
        // reduce stats across the 4 quads (rows live in lanes lm, lm+16, lm+32, lm+48)
        #pragma unroll
        for (int mt = 0; mt < 2; ++mt) {
            float ss = s[mt], qq = sq[mt], mm = mx[mt];
            ss += __shfl_xor(ss, 16); ss += __shfl_xor(ss, 32);
            qq += __shfl_xor(qq, 16); qq += __shfl_xor(qq, 32);
            mm  = fmaxf(mm, __shfl_xor(mm, 16)); mm = fmaxf(mm, __shfl_xor(mm, 32));
            stm[mt][3 * j + 0] = ss * (1.f / 64.f);
            stm[mt][3 * j + 1] = sqrtf(fmaxf(qq * (1.f / 64.f), 1e-8f));
            stm[mt][3 * j + 2] = mm;
        }
    }

    // stat k-step: one MFMA folds all 12 stat contributions via wsT
    {
        short8 sa[2];
        #pragma unroll
        for (int mt = 0; mt < 2; ++mt)
            #pragma unroll
            for (int jj = 0; jj < 8; ++jj) {
                float v;
                if (jj < 4) v = (quad == 0) ? stm[mt][jj] : ((quad == 1) ? stm[mt][8 + jj] : 0.f);
                else        v = (quad == 0) ? stm[mt][jj] : 0.f;
                sa[mt][jj] = f2bf(v);
            }
        #pragma unroll
        for (int nt = 0; nt < 8; ++nt) {
            const short8 b = *(const short8*)(wsT + (size_t)(nt * 16 + lm) * 32 + quad * 8);
            acc[0][nt] = __builtin_amdgcn_mfma_f32_16x16x32_bf16(sa[0], b, acc[0][nt], 0, 0, 0);
            acc[1][nt] = __builtin_amdgcn_mfma_f32_16x16x32_bf16(sa[1], b, acc[1][nt], 0, 0, 0);
        }
    }

    // epilogue: + hidT + b1, GELU, W2 partials, butterfly reduce, softmax
    const float4 b2v = *(const float4*)b2;
    float tcl[4]; float4 efl[4];
    #pragma unroll
    for (int r = 0; r < 4; ++r) {
        const int h = quad * 4 + r;
        tcl[r] = fminf(fmaxf(temp[h], 0.2f), 10.0f);
        efl[r] = *(const float4*)(eps_floor + h * 4);
    }

    #pragma unroll
    for (int mt = 0; mt < 2; ++mt) {
        const int bl = tile0 + mt;
        float p[4][4];
        #pragma unroll
        for (int r = 0; r < 4; ++r)
            #pragma unroll
            for (int c = 0; c < 4; ++c) p[r][c] = 0.f;

        #pragma unroll
        for (int nt = 0; nt < 8; ++nt) {
            const int n = nt * 16 + lm;
            const float hv  = hidT[(size_t)bl * TWO_D + n];
            const float b1v = b1[n];
            const float4 w2v = *(const float4*)(W2 + n * 4);
            #pragma unroll
            for (int r = 0; r < 4; ++r) {
                const float x = acc[mt][nt][r] + hv + b1v;
                const float g = 0.5f * x * (1.0f + erff(x * 0.7071067811865476f));
                p[r][0] = fmaf(g, w2v.x, p[r][0]);
                p[r][1] = fmaf(g, w2v.y, p[r][1]);
                p[r][2] = fmaf(g, w2v.z, p[r][2]);
                p[r][3] = fmaf(g, w2v.w, p[r][3]);
            }
        }
        // reduce over the 16 lanes (n dimension) within each quad
        #pragma unroll
        for (int r = 0; r < 4; ++r)
            #pragma unroll
            for (int c = 0; c < 4; ++c) {
                float v = p[r][c];
                v += __shfl_xor(v, 1); v += __shfl_xor(v, 2);
                v += __shfl_xor(v, 4); v += __shfl_xor(v, 8);
                p[r][c] = v;
            }

        #pragma unroll
        for (int r = 0; r < 4; ++r) {
            const float l0 = p[r][0] + b2v.x;
            const float l1 = p[r][1] + b2v.y;
            const float l2 = p[r][2] + b2v.z;
            const float l3 = p[r][3] + b2v.w;
            const float inv = 1.0f / tcl[r];
            const float m = fmaxf(fmaxf(l0, l1), fmaxf(l2, l3));
            float e0 = expf((l0 - m) * inv);
            float e1 = expf((l1 - m) * inv);
            float e2 = expf((l2 - m) * inv);
            float e3 = expf((l3 - m) * inv);
            const float rsum = 1.0f / (e0 + e1 + e2 + e3);
            float w0 = e0 * rsum, w1 = e1 * rsum, w2 = e2 * rsum, w3 = e3 * rsum;
            w0 = fmaxf(w0, fminf(fmaxf(efl[r].x, 1e-7f), 0.1f));
            w1 = fmaxf(w1, fminf(fmaxf(efl[r].y, 1e-7f), 0.1f));
            w2 = fmaxf(w2, fminf(fmaxf(efl[r].z, 1e-7f), 0.1f));
            w3 = fmaxf(w3, fminf(fmaxf(efl[r].w, 1e-7f), 0.1f));
            const float rs = 1.0f / (w0 + w1 + w2 + w3);
            if (lm == 0) {
                const int pos = bl * 16 + quad * 4 + r;
                float4 ov; ov.x = w0 * rs; ov.y = w1 * rs; ov.z = w2 * rs; ov.w = w3 * rs;
                *(float4*)(out + (size_t)pos * 4) = ov;
            }
        }
    }
}

// ---------------------------------------------------------------- launch
extern "C" void kernel_launch(void* const* d_in, const int* in_sizes, int n_in,
                              void* d_out, int out_size, void* d_ws, size_t ws_size,
                              hipStream_t stream) {
    const float* hidden = (const float*)d_in[0];
    const float* br0    = (const float*)d_in[1];
    const float* br1    = (const float*)d_in[2];
    const float* br2    = (const float*)d_in[3];
    const float* br3    = (const float*)d_in[4];
    const float* W1     = (const float*)d_in[5];
    const float* b1     = (const float*)d_in[6];
    const float* W2     = (const float*)d_in[7];
    const float* b2     = (const float*)d_in[8];
    const float* eps    = (const float*)d_in[9];
    const float* temp   = (const float*)d_in[10];
    float* out = (float*)d_out;

    float* hP0 = (float*)d_ws;                       // 524288 f  (becomes hidT)
    float* hP1 = hP0 + (size_t)NBL * TWO_D;          // 524288 f
    short* WhT = (short*)(hP1 + (size_t)NBL * TWO_D);// 131072 bf16
    short* WbT = WhT + 128 * 1024;                   // 32768 bf16
    short* wsT = WbT + 128 * 256;                    // 4096 bf16

    hipLaunchKernelGGL(k_prep,   dim3(128),  dim3(64),  0, stream, W1, WhT, WbT, wsT);
    hipLaunchKernelGGL(k_hid,    dim3(256),  dim3(64),  0, stream, hidden, WhT, hP0, hP1);
    hipLaunchKernelGGL(k_hidred, dim3(2048), dim3(256), 0, stream, hP0, hP1);
    hipLaunchKernelGGL(k_main,   dim3(2048), dim3(64),  0, stream,
                       br0, br1, br2, br3, WbT, wsT, b1, W2, b2, eps, temp,
                       hP0, out);
}

// Round 4
// 180.277 us; speedup vs baseline: 2.3623x; 1.1518x over previous
//
#include <hip/hip_runtime.h>
#include <math.h>

// Problem constants (B=2, L=2048, H=16, D=64, HID=1024, NB=4)
#define NBL   4096      // B*L
#define NPOS  65536     // B*L*H
#define TWO_D 128
#define HIDN  1024

typedef __attribute__((ext_vector_type(8))) short short8;  // 8 bf16 (4 VGPRs)
typedef __attribute__((ext_vector_type(4))) float f32x4;   // MFMA accumulator

// fp32 -> bf16, round-to-nearest-even (finite inputs)
__device__ inline short f2bf(float f) {
    union { float f; unsigned u; } v; v.f = f;
    unsigned r = (v.u + 0x7FFFu + ((v.u >> 16) & 1u)) >> 16;
    return (short)r;
}

// ws layout:
//   hidT : float [4096][128]   hidden @ W1[:1024]                  (2 MB)
//   WhT  : bf16  [128][1024]   W1 hid part, transposed             (256 KB)
//   WbT  : bf16  [128][256]    W1 branch part, transposed          (64 KB)
//   wsT  : bf16  [128][32]     stat column-sums, transposed, pad   (8 KB)

// ---------------------------------------------------------------- K0: weight prep
// blocks 0..63  : transpose W1 rows [b*16, b*16+16) -> WhT   (LDS transpose)
// blocks 64..79 : transpose W1 rows 1792+[.,.)      -> WbT
// blocks 80..91 : wsum group (b-80) -> wsT column; block 80 zero-pads cols 12..31
__global__ __launch_bounds__(256) void k_prep(const float* __restrict__ W1,
                                              short* __restrict__ WhT,
                                              short* __restrict__ WbT,
                                              short* __restrict__ wsT) {
    __shared__ float lds[16][129];
    const int b = blockIdx.x, t = threadIdx.x;
    if (b < 80) {
        int srcRow0, dstKD, kofs; short* dst;
        if (b < 64) { srcRow0 = b * 16;              dst = WhT; dstKD = 1024; kofs = b * 16; }
        else        { srcRow0 = 1792 + (b - 64) * 16; dst = WbT; dstKD = 256;  kofs = (b - 64) * 16; }
        #pragma unroll
        for (int i = 0; i < 8; ++i) {
            const int idx = i * 256 + t;
            const int row = idx >> 7, col = idx & 127;
            lds[row][col] = W1[(size_t)(srcRow0 + row) * TWO_D + col];   // coalesced
        }
        __syncthreads();
        #pragma unroll
        for (int i = 0; i < 8; ++i) {
            const int idx = i * 256 + t;
            const int n = idx >> 4, k = idx & 15;
            dst[(size_t)n * dstKD + kofs + k] = f2bf(lds[k][n]);
        }
    } else {
        const int i = b - 80;                       // 0..11
        const int j = i / 3, st = i - 3 * j;
        const int base = HIDN + j * 192 + st * 64;
        if (t < 128) {
            float s = 0.f;
            for (int d = 0; d < 64; ++d)
                s += W1[(size_t)(base + d) * TWO_D + t];  // coalesced
            wsT[t * 32 + i] = f2bf(s);
            if (i == 0)
                for (int p = 12; p < 32; ++p) wsT[t * 32 + p] = (short)0;
        }
    }
}

// ---------------------------------------------------------------- K1: hid GEMM (MFMA)
// 256 blocks x 512 thr (8 waves). Block = one 16-row m-tile; wave wid owns
// K slice [wid*128, wid*128+128). LDS reduce across waves, write hidT direct.
__global__ __launch_bounds__(512) void k_hid(const float* __restrict__ hidden,
                                             const short* __restrict__ WhT,
                                             float* __restrict__ hidT) {
    __shared__ float red[7][16][132];               // 59 KB, 132-pitch (2-way max)
    const int t    = threadIdx.x;
    const int lane = t & 63;
    const int wid  = __builtin_amdgcn_readfirstlane(t >> 6);   // 0..7
    const int quad = lane >> 4, lm = lane & 15;
    const int r0   = blockIdx.x * 16;

    f32x4 acc[8];
    #pragma unroll
    for (int nt = 0; nt < 8; ++nt) acc[nt] = (f32x4){0.f, 0.f, 0.f, 0.f};

    #pragma unroll
    for (int kk = 0; kk < 4; ++kk) {
        const int k0 = wid * 128 + kk * 32 + quad * 8;
        const float4 x0 = *(const float4*)(hidden + (size_t)(r0 + lm) * HIDN + k0);
        const float4 x1 = *(const float4*)(hidden + (size_t)(r0 + lm) * HIDN + k0 + 4);
        short8 a;
        a[0] = f2bf(x0.x); a[1] = f2bf(x0.y); a[2] = f2bf(x0.z); a[3] = f2bf(x0.w);
        a[4] = f2bf(x1.x); a[5] = f2bf(x1.y); a[6] = f2bf(x1.z); a[7] = f2bf(x1.w);
        #pragma unroll
        for (int nt = 0; nt < 8; ++nt) {
            const short8 bfr = *(const short8*)(WhT + (size_t)(nt * 16 + lm) * 1024 + k0);
            acc[nt] = __builtin_amdgcn_mfma_f32_16x16x32_bf16(a, bfr, acc[nt], 0, 0, 0);
        }
    }

    if (wid > 0) {
        #pragma unroll
        for (int nt = 0; nt < 8; ++nt)
            #pragma unroll
            for (int r = 0; r < 4; ++r)
                red[wid - 1][quad * 4 + r][nt * 16 + lm] = acc[nt][r];
    }
    __syncthreads();
    if (wid == 0) {
        #pragma unroll
        for (int nt = 0; nt < 8; ++nt)
            #pragma unroll
            for (int r = 0; r < 4; ++r) {
                float v = acc[nt][r];
                #pragma unroll
                for (int w = 0; w < 7; ++w) v += red[w][quad * 4 + r][nt * 16 + lm];
                hidT[(size_t)(r0 + quad * 4 + r) * TWO_D + nt * 16 + lm] = v;
            }
    }
}

// ---------------------------------------------------------------- K2: main fused kernel
// 1024 blocks x 256 thr (4 waves, no LDS/sync). Each wave = one (b,l) m-tile
// (16 heads): branch GEMM K=256 + stat MFMA k-step + epilogue.
__global__ __launch_bounds__(256) void k_main(
    const float* __restrict__ g0, const float* __restrict__ g1,
    const float* __restrict__ g2, const float* __restrict__ g3,
    const short* __restrict__ WbT, const short* __restrict__ wsT,
    const float* __restrict__ b1, const float* __restrict__ W2,
    const float* __restrict__ b2, const float* __restrict__ eps_floor,
    const float* __restrict__ temp, const float* __restrict__ hidT,
    float* __restrict__ out) {

    const int t    = threadIdx.x;
    const int lane = t & 63;
    const int wid  = __builtin_amdgcn_readfirstlane(t >> 6);   // 0..3
    const int quad = lane >> 4, lm = lane & 15;
    const int bl   = blockIdx.x * 4 + wid;          // (b,l) index = m-tile

    f32x4 acc[8];
    #pragma unroll
    for (int nt = 0; nt < 8; ++nt) acc[nt] = (f32x4){0.f, 0.f, 0.f, 0.f};

    float stm[12];
    const float* const bjs[4] = {g0, g1, g2, g3};
    #pragma unroll
    for (int j = 0; j < 4; ++j) {
        const float* __restrict__ bj = bjs[j];
        float s = 0.f, sq = 0.f, mx = -INFINITY;
        #pragma unroll
        for (int half = 0; half < 2; ++half) {
            const int kc  = half * 32 + quad * 8;
            const int pos = bl * 16 + lm;
            const float4 x0 = *(const float4*)(bj + (size_t)pos * 64 + kc);
            const float4 x1 = *(const float4*)(bj + (size_t)pos * 64 + kc + 4);
            s  += x0.x + x0.y + x0.z + x0.w + x1.x + x1.y + x1.z + x1.w;
            sq  = fmaf(x0.x, x0.x, sq); sq = fmaf(x0.y, x0.y, sq);
            sq  = fmaf(x0.z, x0.z, sq); sq = fmaf(x0.w, x0.w, sq);
            sq  = fmaf(x1.x, x1.x, sq); sq = fmaf(x1.y, x1.y, sq);
            sq  = fmaf(x1.w, x1.w, sq); sq = fmaf(x1.z, x1.z, sq);
            mx  = fmaxf(mx, fmaxf(fmaxf(x0.x, x0.y), fmaxf(x0.z, x0.w)));
            mx  = fmaxf(mx, fmaxf(fmaxf(x1.x, x1.y), fmaxf(x1.z, x1.w)));
            short8 a;
            a[0] = f2bf(x0.x); a[1] = f2bf(x0.y); a[2] = f2bf(x0.z); a[3] = f2bf(x0.w);
            a[4] = f2bf(x1.x); a[5] = f2bf(x1.y); a[6] = f2bf(x1.z); a[7] = f2bf(x1.w);
            const int kg = j * 64 + half * 32 + quad * 8;
            #pragma unroll
            for (int nt = 0; nt < 8; ++nt) {
                const short8 bfr = *(const short8*)(WbT + (size_t)(nt * 16 + lm) * 256 + kg);
                acc[nt] = __builtin_amdgcn_mfma_f32_16x16x32_bf16(a, bfr, acc[nt], 0, 0, 0);
            }
        }
        // reduce stats across the 4 quads (row lives in lanes lm, lm+16, lm+32, lm+48)
        float ss = s, qq = sq, mm = mx;
        ss += __shfl_xor(ss, 16); ss += __shfl_xor(ss, 32);
        qq += __shfl_xor(qq, 16); qq += __shfl_xor(qq, 32);
        mm  = fmaxf(mm, __shfl_xor(mm, 16)); mm = fmaxf(mm, __shfl_xor(mm, 32));
        stm[3 * j + 0] = ss * (1.f / 64.f);
        stm[3 * j + 1] = sqrtf(fmaxf(qq * (1.f / 64.f), 1e-8f));
        stm[3 * j + 2] = mm;
    }

    // stat k-step: one MFMA folds all 12 stat contributions via wsT
    {
        short8 sa;
        #pragma unroll
        for (int jj = 0; jj < 8; ++jj) {
            float v;
            if (jj < 4) v = (quad == 0) ? stm[jj] : ((quad == 1) ? stm[8 + jj] : 0.f);
            else        v = (quad == 0) ? stm[jj] : 0.f;
            sa[jj] = f2bf(v);
        }
        #pragma unroll
        for (int nt = 0; nt < 8; ++nt) {
            const short8 bfr = *(const short8*)(wsT + (size_t)(nt * 16 + lm) * 32 + quad * 8);
            acc[nt] = __builtin_amdgcn_mfma_f32_16x16x32_bf16(sa, bfr, acc[nt], 0, 0, 0);
        }
    }

    // epilogue: + hidT + b1, GELU, W2 partials, butterfly reduce, softmax
    const float4 b2v = *(const float4*)b2;
    float tcl[4]; float4 efl[4];
    #pragma unroll
    for (int r = 0; r < 4; ++r) {
        const int h = quad * 4 + r;
        tcl[r] = fminf(fmaxf(temp[h], 0.2f), 10.0f);
        efl[r] = *(const float4*)(eps_floor + h * 4);
    }

    float p[4][4];
    #pragma unroll
    for (int r = 0; r < 4; ++r)
        #pragma unroll
        for (int c = 0; c < 4; ++c) p[r][c] = 0.f;

    #pragma unroll
    for (int nt = 0; nt < 8; ++nt) {
        const int n = nt * 16 + lm;
        const float hv  = hidT[(size_t)bl * TWO_D + n];
        const float b1v = b1[n];
        const float4 w2v = *(const float4*)(W2 + n * 4);
        #pragma unroll
        for (int r = 0; r < 4; ++r) {
            const float x = acc[nt][r] + hv + b1v;
            const float g = 0.5f * x * (1.0f + erff(x * 0.7071067811865476f));
            p[r][0] = fmaf(g, w2v.x, p[r][0]);
            p[r][1] = fmaf(g, w2v.y, p[r][1]);
            p[r][2] = fmaf(g, w2v.z, p[r][2]);
            p[r][3] = fmaf(g, w2v.w, p[r][3]);
        }
    }
    #pragma unroll
    for (int r = 0; r < 4; ++r)
        #pragma unroll
        for (int c = 0; c < 4; ++c) {
            float v = p[r][c];
            v += __shfl_xor(v, 1); v += __shfl_xor(v, 2);
            v += __shfl_xor(v, 4); v += __shfl_xor(v, 8);
            p[r][c] = v;
        }

    #pragma unroll
    for (int r = 0; r < 4; ++r) {
        const float l0 = p[r][0] + b2v.x;
        const float l1 = p[r][1] + b2v.y;
        const float l2 = p[r][2] + b2v.z;
        const float l3 = p[r][3] + b2v.w;
        const float inv = 1.0f / tcl[r];
        const float m = fmaxf(fmaxf(l0, l1), fmaxf(l2, l3));
        float e0 = expf((l0 - m) * inv);
        float e1 = expf((l1 - m) * inv);
        float e2 = expf((l2 - m) * inv);
        float e3 = expf((l3 - m) * inv);
        const float rsum = 1.0f / (e0 + e1 + e2 + e3);
        float w0 = e0 * rsum, w1 = e1 * rsum, w2 = e2 * rsum, w3 = e3 * rsum;
        w0 = fmaxf(w0, fminf(fmaxf(efl[r].x, 1e-7f), 0.1f));
        w1 = fmaxf(w1, fminf(fmaxf(efl[r].y, 1e-7f), 0.1f));
        w2 = fmaxf(w2, fminf(fmaxf(efl[r].z, 1e-7f), 0.1f));
        w3 = fmaxf(w3, fminf(fmaxf(efl[r].w, 1e-7f), 0.1f));
        const float rs = 1.0f / (w0 + w1 + w2 + w3);
        if (lm == 0) {
            const int pos = bl * 16 + quad * 4 + r;
            float4 ov; ov.x = w0 * rs; ov.y = w1 * rs; ov.z = w2 * rs; ov.w = w3 * rs;
            *(float4*)(out + (size_t)pos * 4) = ov;
        }
    }
}

// ---------------------------------------------------------------- launch
extern "C" void kernel_launch(void* const* d_in, const int* in_sizes, int n_in,
                              void* d_out, int out_size, void* d_ws, size_t ws_size,
                              hipStream_t stream) {
    const float* hidden = (const float*)d_in[0];
    const float* br0    = (const float*)d_in[1];
    const float* br1    = (const float*)d_in[2];
    const float* br2    = (const float*)d_in[3];
    const float* br3    = (const float*)d_in[4];
    const float* W1     = (const float*)d_in[5];
    const float* b1     = (const float*)d_in[6];
    const float* W2     = (const float*)d_in[7];
    const float* b2     = (const float*)d_in[8];
    const float* eps    = (const float*)d_in[9];
    const float* temp   = (const float*)d_in[10];
    float* out = (float*)d_out;

    float* hidT = (float*)d_ws;                        // 524288 f
    short* WhT  = (short*)(hidT + (size_t)NBL * TWO_D);// 131072 bf16
    short* WbT  = WhT + 128 * 1024;                    // 32768 bf16
    short* wsT  = WbT + 128 * 256;                     // 4096 bf16

    hipLaunchKernelGGL(k_prep, dim3(92),   dim3(256), 0, stream, W1, WhT, WbT, wsT);
    hipLaunchKernelGGL(k_hid,  dim3(256),  dim3(512), 0, stream, hidden, WhT, hidT);
    hipLaunchKernelGGL(k_main, dim3(1024), dim3(256), 0, stream,
                       br0, br1, br2, br3, WbT, wsT, b1, W2, b2, eps, temp,
                       hidT, out);
}